// Round 8
// baseline (341.545 us; speedup 1.0000x reference)
//
#include <hip/hip_runtime.h>

// Problem constants (fixed shape)
// N=8192 tokens, D=1280, H=16 heads, K=80 head dim (pad 96), S=16 segs, L=512
#define LOG2E 1.44269504088896340736f
#define ATT_SCALE 0.11180339887498949f  // 80^-0.5

typedef _Float16 half8 __attribute__((ext_vector_type(8)));
typedef _Float16 half4v __attribute__((ext_vector_type(4)));
typedef __fp16 fp16x2 __attribute__((ext_vector_type(2)));
typedef float f32x4 __attribute__((ext_vector_type(4)));

#define MFMA(a, b, c) __builtin_amdgcn_mfma_f32_16x16x32_f16((a), (b), (c), 0, 0, 0)

__device__ __forceinline__ void async16(const _Float16* g, _Float16* l) {
  __builtin_amdgcn_global_load_lds(
      (const __attribute__((address_space(1))) unsigned int*)g,
      (__attribute__((address_space(3))) unsigned int*)l,
      16, 0, 0);
}

#define FENCE() asm volatile("" ::: "memory")
// fenced barrier (used by gemm_k, proven R7 structure)
#define PHB()                                   \
  do {                                          \
    FENCE();                                    \
    __builtin_amdgcn_s_barrier();               \
    FENCE();                                    \
  } while (0)
// bare barrier (gemm256 R8): NO memory fence, so the compiler may hoist
// next-phase ds_reads into the current MFMA window (m201's overlap; safe
// under double-buffering — every read's data landed at the vmcnt checkpoint
// one full tile earlier). vmcnt asms keep their memory clobber and remain
// the hard fences of the staging protocol.
#define BARE_BAR() __builtin_amdgcn_s_barrier()

// ---------------- fp32 -> fp16 convert (hidden) ----------------
__global__ __launch_bounds__(256) void cvt_k(const float* __restrict__ in,
                                             _Float16* __restrict__ out, int n4) {
  int i = blockIdx.x * 256 + threadIdx.x;
  if (i < n4) {
    f32x4 v = ((const f32x4*)in)[i];
    half4v hv;
    hv[0] = (_Float16)v[0]; hv[1] = (_Float16)v[1];
    hv[2] = (_Float16)v[2]; hv[3] = (_Float16)v[3];
    ((half4v*)out)[i] = hv;
  }
}

// ---------------- transpose + convert: in R x C fp32 -> out C x R fp16 ----------
__global__ __launch_bounds__(256) void transpose_cvt_k(const float* __restrict__ in,
                                                       _Float16* __restrict__ out,
                                                       int R, int C) {
  __shared__ float tile[32][33];
  const int tx = threadIdx.x & 31, ty = threadIdx.x >> 5;
  const int c0 = blockIdx.x * 32, r0 = blockIdx.y * 32;
#pragma unroll
  for (int i = 0; i < 32; i += 8)
    tile[ty + i][tx] = in[(size_t)(r0 + ty + i) * C + c0 + tx];
  __syncthreads();
#pragma unroll
  for (int i = 0; i < 32; i += 8)
    out[(size_t)(c0 + ty + i) * R + r0 + tx] = (_Float16)tile[tx][ty + i];
}

// ---------------- GEMM0: 256x256 tile, BK=64, 4-phase K-loop (R8) -------------
// C = A(8192x1280) * BT^T (3840x1280), scatter epilogue -> Qf/Kf/VTf
//
// R8 = R4 schedule (proven 115 us, conflicts 0, FETCH ideal) with two
// source-level changes targeting the closed cycle model (VALU addr ~19K cyc
// + fence-serialized phases):
//  (1) bare s_barrier (no fences) -> compiler may hoist phase-p ds_reads
//      into phase p-1's MFMA window. Hoist-safety audit: every buffer read
//      at tile t was drained by the vmcnt checkpoint at tile t-1 q3, which
//      precedes any barrier a read could hoist across; vmcnt asms retain
//      memory clobbers and bound all motion.
//  (2) ds_read base hoisting: pg=(kk*4+quad)^(l16&7) == [kk^b2]*4 | [quad^
//      (l16&3)] (b2=(l16>>2)&1, disjoint bits) -> 2 precomputed bases per
//      operand; all 24 reads/tile become base + compile-time imm offset
//      (max 47104 B < 64K) -> zero per-read VALU.
//
// Schedule per tile t (buf=t&1):
//   q0: BAR; ldA(r0)8+ldB(c0)4; stage A(t+1)h0; MFMA(r0,c0)
//   q1: BAR; ldB(c1)4;          stage A(t+1)h1; MFMA(r0,c1)
//   q2: BAR; ldA(r1)8;          stage B(t+2)h0; MFMA(r1,c1)
//   q3: BAR;                    stage B(t+2)h1; vmcnt(4); MFMA(r1,c0)
// vmcnt(4) counted, never 0 mid-loop (T4).
// XCD map: XCD x owns tm in [4x,4x+4), sweeps tn -> A 2.6MB L2-pinned.
// Swizzle (rule #21): LDS dest linear; source pre-permuted lg=g^(row&7);
// reads apply the same involution.
__global__ __launch_bounds__(512, 2) void gemm256_k(const _Float16* __restrict__ A,
                                                    const _Float16* __restrict__ BT,
                                                    const float* __restrict__ bias,
                                                    _Float16* __restrict__ Qf,
                                                    _Float16* __restrict__ Kf,
                                                    _Float16* __restrict__ VTf) {
  __shared__ _Float16 sA[2][2][128 * 64];  // [buf][half][row*64 + col], 64 KB
  __shared__ _Float16 sB[2][2][128 * 64];  // 64 KB
  const int tid = threadIdx.x;
  const int wave = tid >> 6, lane = tid & 63;
  const int quad = lane >> 4, l16 = lane & 15;
  const int wm = wave >> 2, wn = wave & 3;      // wave grid 2M x 4N
  const int bh = wn >> 1, brb = (wn & 1) * 64;  // B half + row base within half
  const int KD = 1280, NT = 20;                 // 20 K-tiles of 64

  // A-pinned XCD mapping
  const int id = blockIdx.x;
  const int xcd = id & 7;
  const int qq = (id >> 3) & 3;
  const int tn = id >> 5;           // 0..14
  const int tm = xcd * 4 + qq;      // 0..31
  const int m0 = tm * 256, n0 = tn * 256;

  f32x4 acc[8][4] = {};

  // hoisted ds_read bases (verified vs original formula on concrete lanes)
  const int b2 = (l16 >> 2) & 1, q3x = quad ^ (l16 & 3);
  const int pg0 = b2 * 4 + q3x;          // kk=0 group
  const int pg1 = (4 - b2 * 4) + q3x;    // kk=1 group
  const _Float16* aB0 = &sA[0][wm][0] + l16 * 64 + pg0 * 8;
  const _Float16* aB1 = &sA[0][wm][0] + l16 * 64 + pg1 * 8;
  const _Float16* bB0 = &sB[0][bh][0] + brb * 64 + l16 * 64 + pg0 * 8;
  const _Float16* bB1 = &sB[0][bh][0] + brb * 64 + l16 * 64 + pg1 * 8;

  auto stageA = [&](int buf, int half, int kt) {
#pragma unroll
    for (int c = 0; c < 2; ++c) {
      const int s = c * 512 + wave * 64 + lane;
      const int row = s >> 3;
      const int lg = (s & 7) ^ (row & 7);
      async16(A + (size_t)(m0 + half * 128 + row) * KD + kt * 64 + lg * 8,
              &sA[buf][half][(size_t)(c * 512 + wave * 64) * 8]);
    }
  };
  auto stageB = [&](int buf, int half, int kt) {
#pragma unroll
    for (int c = 0; c < 2; ++c) {
      const int s = c * 512 + wave * 64 + lane;
      const int row = s >> 3;
      const int lg = (s & 7) ^ (row & 7);
      async16(BT + (size_t)(n0 + half * 128 + row) * KD + kt * 64 + lg * 8,
              &sB[buf][half][(size_t)(c * 512 + wave * 64) * 8]);
    }
  };
  // A fragments: base + imm (buf/rh/i constant-folded via unroll)
  auto ldA = [&](half8* af, int buf, int rh) {
#pragma unroll
    for (int i = 0; i < 4; ++i) {
      af[i * 2 + 0] = *(const half8*)(aB0 + buf * 16384 + rh * 4096 + i * 1024);
      af[i * 2 + 1] = *(const half8*)(aB1 + buf * 16384 + rh * 4096 + i * 1024);
    }
  };
  auto ldB = [&](half8* bf, int buf, int ch) {
#pragma unroll
    for (int j = 0; j < 2; ++j) {
      bf[j * 2 + 0] = *(const half8*)(bB0 + buf * 16384 + ch * 2048 + j * 1024);
      bf[j * 2 + 1] = *(const half8*)(bB1 + buf * 16384 + ch * 2048 + j * 1024);
    }
  };
  auto mmaq = [&](int r, int c, const half8* af, const half8* bf) {
#pragma unroll
    for (int i = 0; i < 4; ++i)
#pragma unroll
      for (int j = 0; j < 2; ++j)
#pragma unroll
        for (int kk = 0; kk < 2; ++kk)
          acc[r * 4 + i][c * 2 + j] =
              MFMA(af[i * 2 + kk], bf[j * 2 + kk], acc[r * 4 + i][c * 2 + j]);
  };

  // prologue: tile0 A+B, tile1 B; vmcnt(4) leaves B(t1)x4 in flight
  stageA(0, 0, 0); stageA(0, 1, 0);
  stageB(0, 0, 0); stageB(0, 1, 0);
  stageB(1, 0, 1); stageB(1, 1, 1);
  asm volatile("s_waitcnt vmcnt(4)" ::: "memory");

  half8 af[8], bf0[4], bf1[4];
#pragma unroll 2
  for (int t = 0; t < NT; ++t) {
    const int buf = t & 1;

    // ---- q0: MFMA(r0,c0); stage A(t+1) h0
    BARE_BAR();
    ldA(af, buf, 0);
    ldB(bf0, buf, 0);
    if (t + 1 < NT) stageA(buf ^ 1, 0, t + 1);
    __builtin_amdgcn_s_setprio(1);
    mmaq(0, 0, af, bf0);
    __builtin_amdgcn_s_setprio(0);

    // ---- q1: MFMA(r0,c1); stage A(t+1) h1
    BARE_BAR();
    ldB(bf1, buf, 1);
    if (t + 1 < NT) stageA(buf ^ 1, 1, t + 1);
    __builtin_amdgcn_s_setprio(1);
    mmaq(0, 1, af, bf1);
    __builtin_amdgcn_s_setprio(0);

    // ---- q2: MFMA(r1,c1); stage B(t+2) h0 (sB[buf] reads finished in q1)
    BARE_BAR();
    ldA(af, buf, 1);
    if (t + 2 < NT) stageB(buf, 0, t + 2);
    __builtin_amdgcn_s_setprio(1);
    mmaq(1, 1, af, bf1);
    __builtin_amdgcn_s_setprio(0);

    // ---- q3: MFMA(r1,c0); stage B(t+2) h1; K-tile vmcnt checkpoint
    BARE_BAR();
    if (t + 2 < NT) stageB(buf, 1, t + 2);
    if (t == NT - 2)
      asm volatile("s_waitcnt vmcnt(0)" ::: "memory");  // final drain
    else if (t < NT - 2)
      asm volatile("s_waitcnt vmcnt(4)" ::: "memory");  // counted, never 0
    __builtin_amdgcn_s_setprio(1);
    mmaq(1, 0, af, bf0);
    __builtin_amdgcn_s_setprio(0);
  }

  // scatter epilogue: C row = quad*4+reg, col = l16 within fragment [m89-verified]
#pragma unroll
  for (int ridx = 0; ridx < 8; ++ridx) {
#pragma unroll
    for (int cidx = 0; cidx < 4; ++cidx) {
      const int col = n0 + wn * 64 + cidx * 16 + l16;
      const float bv = bias[col];
      const int rowb = m0 + wm * 128 + ridx * 16 + quad * 4;
      const int which = col / 1280;
      const int rem = col - which * 1280;
      const int h = rem / 80;
      const int kk = rem - h * 80;
#pragma unroll
      for (int r = 0; r < 4; ++r) {
        const float v = acc[ridx][cidx][r] + bv;
        const int mrow = rowb + r;
        const int s = mrow >> 9, l = mrow & 511;
        const int shh = s * 16 + h;
        if (which == 0)
          Qf[((size_t)shh * 512 + l) * 96 + kk] = (_Float16)v;
        else if (which == 1)
          Kf[((size_t)shh * 512 + l) * 96 + kk] = (_Float16)v;
        else
          VTf[((size_t)shh * 80 + kk) * 512 + l] = (_Float16)v;
      }
    }
  }
}

// ---------------- GEMM1 (proj): 128x128 tile, BK=64, 2-phase, 2 blocks/CU -----
// R7 verbatim (won -19.5 us): 4 waves, per-wave 64x64, 64 KB LDS -> 2
// independent blocks/CU; stage(t+1) first, one vmcnt(0)+barrier per tile.
__global__ __launch_bounds__(256) void gemm_k(const _Float16* __restrict__ A,
                                              const _Float16* __restrict__ BT,
                                              const float* __restrict__ bias,
                                              float* __restrict__ Out) {
  __shared__ _Float16 sA[2][128 * 64];  // 32 KB
  __shared__ _Float16 sB[2][128 * 64];  // 32 KB
  const int tid = threadIdx.x;
  const int wave = tid >> 6, lane = tid & 63;
  const int quad = lane >> 4, l16 = lane & 15;
  const int wm = wave >> 1, wn = wave & 1;  // wave grid 2M x 2N, per-wave 64x64
  const int KD = 1280, NT = 20;

  const int m0 = blockIdx.x * 128;
  const int n0 = blockIdx.y * 128;

  f32x4 acc[4][4] = {};

  auto stage = [&](_Float16* dst, const _Float16* src, int rbase, int kt) {
#pragma unroll
    for (int c = 0; c < 4; ++c) {
      const int s = c * 256 + tid;
      const int row = s >> 3;
      const int lg = (s & 7) ^ (row & 7);
      async16(src + (size_t)(rbase + row) * KD + kt * 64 + lg * 8,
              dst + (size_t)(c * 256 + wave * 64) * 8);
    }
  };
  auto ldA = [&](half8* af, const _Float16* hp) {
#pragma unroll
    for (int i = 0; i < 4; ++i)
#pragma unroll
      for (int kk = 0; kk < 2; ++kk) {
        const int lrow = wm * 64 + i * 16 + l16;
        const int pg = (kk * 4 + quad) ^ (l16 & 7);
        af[i * 2 + kk] = *(const half8*)(hp + lrow * 64 + pg * 8);
      }
  };
  auto ldB = [&](half8* bf, const _Float16* hp) {
#pragma unroll
    for (int j = 0; j < 4; ++j)
#pragma unroll
      for (int kk = 0; kk < 2; ++kk) {
        const int brow = wn * 64 + j * 16 + l16;
        const int pg = (kk * 4 + quad) ^ (l16 & 7);
        bf[j * 2 + kk] = *(const half8*)(hp + brow * 64 + pg * 8);
      }
  };

  stage(&sA[0][0], A, m0, 0);
  stage(&sB[0][0], BT, n0, 0);
  asm volatile("s_waitcnt vmcnt(0)" ::: "memory");
  PHB();

  half8 af[8], bf[8];
#pragma unroll 2
  for (int t = 0; t < NT; ++t) {
    const int buf = t & 1;
    if (t + 1 < NT) {
      stage(&sA[buf ^ 1][0], A, m0, t + 1);
      stage(&sB[buf ^ 1][0], BT, n0, t + 1);
    }
    ldA(af, &sA[buf][0]);
    ldB(bf, &sB[buf][0]);
    __builtin_amdgcn_s_setprio(1);
#pragma unroll
    for (int i = 0; i < 4; ++i)
#pragma unroll
      for (int j = 0; j < 4; ++j)
#pragma unroll
        for (int kk = 0; kk < 2; ++kk)
          acc[i][j] = MFMA(af[i * 2 + kk], bf[j * 2 + kk], acc[i][j]);
    __builtin_amdgcn_s_setprio(0);
    if (t + 1 < NT)
      asm volatile("s_waitcnt vmcnt(0)" ::: "memory");  // next tile landed
    PHB();
  }

#pragma unroll
  for (int i = 0; i < 4; ++i) {
#pragma unroll
    for (int j = 0; j < 4; ++j) {
      const int col = n0 + wn * 64 + j * 16 + l16;
      const float bv = bias[col];
      const int rowb = m0 + wm * 64 + i * 16 + quad * 4;
#pragma unroll
      for (int r = 0; r < 4; ++r)
        Out[(size_t)(rowb + r) * 1280 + col] = acc[i][j][r] + bv;
    }
  }
}

// ---------------- RoPE in-place on Qf/Kf + zero the k-pad [80,96), vectorized --
__global__ __launch_bounds__(256) void rope_k(_Float16* __restrict__ Qf,
                                              _Float16* __restrict__ Kf,
                                              const float* __restrict__ cosNK,
                                              const float* __restrict__ sinNK) {
  const int gid = blockIdx.x * 256 + threadIdx.x;  // 2,621,440 = 262144 rows * 10
  const int jt = gid % 10;
  const int row = gid / 10;
  const int qk = row >> 17;
  const int r = row & 131071;      // (s*16+h)*512 + l
  _Float16* buf = qk ? Kf : Qf;
  const int l = r & 511;
  const int s = r >> 13;
  const int t = s * 512 + l;
  const size_t base = (size_t)r * 96;
  const int j0 = jt * 4;

  half4v v1 = *(const half4v*)(buf + base + j0);
  half4v v2 = *(const half4v*)(buf + base + 40 + j0);
  f32x4 c1 = *(const f32x4*)(cosNK + (size_t)t * 80 + j0);
  f32x4 s1 = *(const f32x4*)(sinNK + (size_t)t * 80 + j0);
  f32x4 c2 = *(const f32x4*)(cosNK + (size_t)t * 80 + 40 + j0);
  f32x4 s2 = *(const f32x4*)(sinNK + (size_t)t * 80 + 40 + j0);
  half4v o1, o2;
#pragma unroll
  for (int e = 0; e < 4; ++e) {
    const float a = (float)v1[e], b = (float)v2[e];
    o1[e] = (_Float16)(a * c1[e] - b * s1[e]);
    o2[e] = (_Float16)(b * c2[e] + a * s2[e]);
  }
  *(half4v*)(buf + base + j0) = o1;
  *(half4v*)(buf + base + 40 + j0) = o2;
  if (jt < 2) {  // zero pad kk = 80..95 (two half8 stores)
    half8 z = {};
    *(half8*)(buf + base + 80 + jt * 8) = z;
  }
}

// ---------------- flash attention (S^T form, no-max softmax, sum via ones) ----
__global__ __launch_bounds__(256) void attn_k(const _Float16* __restrict__ Qf,
                                              const _Float16* __restrict__ Kf,
                                              const _Float16* __restrict__ VTf,
                                              _Float16* __restrict__ attnA) {
  __shared__ _Float16 sP[128 * 72];   // P tile, row stride 72
  __shared__ _Float16 sK[64 * 104];   // K tile, row stride 104 (conflict-free)
  __shared__ _Float16 sV[96 * 72];    // rows 0..79: V^T tile; rows 80..95: ones
  const int tid = threadIdx.x;
  const int wave = tid >> 6, lane = tid & 63;
  const int quad = lane >> 4, l16 = lane & 15;
  const int shh = blockIdx.x;  // s*16+h
  const int qt = blockIdx.y;   // 0..3
  const int h = shh & 15;
  const int s = shh >> 4;

  const _Float16* Qb = Qf + ((size_t)shh * 512 + qt * 128) * 96;
  const _Float16* Kb0 = Kf + (size_t)shh * 512 * 96;
  const _Float16* Vb0 = VTf + (size_t)shh * 80 * 512;

  // Q fragments straight from global (rows are lane-exact), pre-scaled
  const _Float16 c1h = (_Float16)(ATT_SCALE * LOG2E);
  half8 qf[2][3];
#pragma unroll
  for (int rt = 0; rt < 2; ++rt)
#pragma unroll
    for (int ks = 0; ks < 3; ++ks) {
      half8 t = *(const half8*)(Qb + (size_t)(wave * 32 + rt * 16 + l16) * 96 +
                                ks * 32 + quad * 8);
#pragma unroll
      for (int e = 0; e < 8; ++e) t[e] *= c1h;
      qf[rt][ks] = t;
    }

  // ones rows for the row-sum trick
  for (int idx = tid; idx < 16 * 72; idx += 256) sV[80 * 72 + idx] = (_Float16)1.f;

  f32x4 o[2][6] = {};  // ft 0..4: output features; ft 5: row sum

  for (int kc = 0; kc < 8; ++kc) {
    __syncthreads();  // prev iter LDS reads done (iter0: ones visible)
    // K tile -> sK, padded stride 104 halves (208 B), masked DMA (13 chunks)
    const _Float16* Kb = Kb0 + (size_t)kc * 64 * 96;
#pragma unroll
    for (int c = 0; c < 4; ++c) {
      const int j = wave + 4 * c;
      if (j < 13) {
        const int off = j * 1024 + lane * 16;  // LDS byte offset
        const int krow = off / 208;
        const int kcol = off - krow * 208;     // bytes within padded row
        if (kcol < 192)
          async16(Kb + (size_t)krow * 96 + (kcol >> 1), &sK[j * 512]);
      }
    }
    // V^T tile -> sV, padded stride 72 halves (144 B), masked DMA (12 chunks)
#pragma unroll
    for (int c = 0; c < 3; ++c) {
      const int j = wave + 4 * c;
      const int off = j * 1024 + lane * 16;
      const int vrow = off / 144;
      const int colb = off - vrow * 144;
      if (vrow < 80 && colb < 128)
        async16(Vb0 + (size_t)vrow * 512 + kc * 64 + (colb >> 1), &sV[j * 512]);
    }
    __syncthreads();

    // S^T = K Q^T (operand swap): lane holds S[q=l16][k=mt*16+quad*4+r]
    f32x4 sacc[2][4] = {};  // [rt][mt]
#pragma unroll
    for (int mt = 0; mt < 4; ++mt) {
#pragma unroll
      for (int ks = 0; ks < 3; ++ks) {
        half8 kb = *(const half8*)&sK[(mt * 16 + l16) * 104 + ks * 32 + quad * 8];
        sacc[0][mt] = MFMA(kb, qf[0][ks], sacc[0][mt]);
        sacc[1][mt] = MFMA(kb, qf[1][ks], sacc[1][mt]);
      }
    }

    // p = exp2(s), packed pairs (consecutive k!), one b64 store per (rt,mt)
#pragma unroll
    for (int rt = 0; rt < 2; ++rt) {
#pragma unroll
      for (int mt = 0; mt < 4; ++mt) {
        union { fp16x2 h2[2]; half4v h4; } u;
        u.h2[0] = __builtin_amdgcn_cvt_pkrtz(
            __builtin_amdgcn_exp2f(sacc[rt][mt][0]),
            __builtin_amdgcn_exp2f(sacc[rt][mt][1]));
        u.h2[1] = __builtin_amdgcn_cvt_pkrtz(
            __builtin_amdgcn_exp2f(sacc[rt][mt][2]),
            __builtin_amdgcn_exp2f(sacc[rt][mt][3]));
        *(half4v*)&sP[(wave * 32 + rt * 16 + l16) * 72 + mt * 16 + quad * 4] = u.h4;
      }
    }
    // sP rows are wave-private: per-wave LDS ordering suffices, no barrier

    // O += P V  (ft=5 accumulates the row sum via the ones rows)
#pragma unroll
    for (int ks = 0; ks < 2; ++ks) {
      half8 pa[2];
      pa[0] = *(const half8*)&sP[(wave * 32 + 0 + l16) * 72 + ks * 32 + quad * 8];
      pa[1] = *(const half8*)&sP[(wave * 32 + 16 + l16) * 72 + ks * 32 + quad * 8];
#pragma unroll
      for (int ft = 0; ft < 6; ++ft) {
        half8 vb = *(const half8*)&sV[(ft * 16 + l16) * 72 + ks * 32 + quad * 8];
        o[0][ft] = MFMA(pa[0], vb, o[0][ft]);
        o[1][ft] = MFMA(pa[1], vb, o[1][ft]);
      }
    }
  }

  // epilogue: divide by row sum, store fp16 into attnA [token][h*80+f]
#pragma unroll
  for (int rt = 0; rt < 2; ++rt) {
#pragma unroll
    for (int r = 0; r < 4; ++r) {
      const float inv = 1.0f / o[rt][5][r];
      const int token = s * 512 + qt * 128 + wave * 32 + rt * 16 + quad * 4 + r;
#pragma unroll
      for (int ft = 0; ft < 5; ++ft)
        attnA[(size_t)token * 1280 + h * 80 + ft * 16 + l16] =
            (_Float16)(o[rt][ft][r] * inv);
    }
  }
}

extern "C" void kernel_launch(void* const* d_in, const int* in_sizes, int n_in,
                              void* d_out, int out_size, void* d_ws, size_t ws_size,
                              hipStream_t stream) {
  (void)in_sizes; (void)n_in; (void)out_size; (void)ws_size;
  const float* hidden = (const float*)d_in[0];
  const float* cosNK = (const float*)d_in[2];
  const float* sinNK = (const float*)d_in[3];
  const float* qkv_w = (const float*)d_in[4];
  const float* qkv_b = (const float*)d_in[5];
  const float* proj_w = (const float*)d_in[6];
  const float* proj_b = (const float*)d_in[7];
  float* out = (float*)d_out;

  char* ws = (char*)d_ws;
  _Float16* hA    = (_Float16*)(ws);                   // 8192x1280        20971520 B
  _Float16* wT    = (_Float16*)(ws + 20971520);        // 3840x1280         9830400 B
  _Float16* projT = (_Float16*)(ws + 30801920);        // 1280x1280         3276800 B
  _Float16* Qf    = (_Float16*)(ws + 34078720);        // 256x512x96       25165824 B
  _Float16* Kf    = (_Float16*)(ws + 59244544);        // 256x512x96       25165824 B
  _Float16* VTf   = (_Float16*)(ws + 84410368);        // 256x80x512       20971520 B
  _Float16* attnA = (_Float16*)(ws + 105381888);       // 8192x1280        20971520 B

  cvt_k<<<10240, 256, 0, stream>>>(hidden, hA, 2621440);
  transpose_cvt_k<<<dim3(120, 40), 256, 0, stream>>>(qkv_w, wT, 1280, 3840);
  transpose_cvt_k<<<dim3(40, 40), 256, 0, stream>>>(proj_w, projT, 1280, 1280);
  gemm256_k<<<480, 512, 0, stream>>>(hA, wT, qkv_b, Qf, Kf, VTf);
  rope_k<<<10240, 256, 0, stream>>>(Qf, Kf, cosNK, sinNK);
  attn_k<<<dim3(256, 4), 256, 0, stream>>>(Qf, Kf, VTf, attnA);
  gemm_k<<<dim3(64, 10), 256, 0, stream>>>(attnA, projT, proj_b, out);
}

// Round 9
// 340.862 us; speedup vs baseline: 1.0020x; 1.0020x over previous
//
#include <hip/hip_runtime.h>

// Problem constants (fixed shape)
// N=8192 tokens, D=1280, H=16 heads, K=80 head dim (pad 96), S=16 segs, L=512
#define LOG2E 1.44269504088896340736f
#define ATT_SCALE 0.11180339887498949f  // 80^-0.5

typedef _Float16 half8 __attribute__((ext_vector_type(8)));
typedef _Float16 half4v __attribute__((ext_vector_type(4)));
typedef __fp16 fp16x2 __attribute__((ext_vector_type(2)));
typedef float f32x4 __attribute__((ext_vector_type(4)));

#define MFMA(a, b, c) __builtin_amdgcn_mfma_f32_16x16x32_f16((a), (b), (c), 0, 0, 0)

__device__ __forceinline__ void async16(const _Float16* g, _Float16* l) {
  __builtin_amdgcn_global_load_lds(
      (const __attribute__((address_space(1))) unsigned int*)g,
      (__attribute__((address_space(3))) unsigned int*)l,
      16, 0, 0);
}

#define FENCE() asm volatile("" ::: "memory")
// fenced barrier (used by gemm_k, proven R7 structure)
#define PHB()                                   \
  do {                                          \
    FENCE();                                    \
    __builtin_amdgcn_s_barrier();               \
    FENCE();                                    \
  } while (0)
// bare barrier (gemm256, R8 — equal to R4 within noise; kept)
#define BARE_BAR() __builtin_amdgcn_s_barrier()

// ---------------- fp32 -> fp16 convert (hidden) ----------------
__global__ __launch_bounds__(256) void cvt_k(const float* __restrict__ in,
                                             _Float16* __restrict__ out, int n4) {
  int i = blockIdx.x * 256 + threadIdx.x;
  if (i < n4) {
    f32x4 v = ((const f32x4*)in)[i];
    half4v hv;
    hv[0] = (_Float16)v[0]; hv[1] = (_Float16)v[1];
    hv[2] = (_Float16)v[2]; hv[3] = (_Float16)v[3];
    ((half4v*)out)[i] = hv;
  }
}

// ---------------- transpose + convert: in R x C fp32 -> out C x R fp16 ----------
__global__ __launch_bounds__(256) void transpose_cvt_k(const float* __restrict__ in,
                                                       _Float16* __restrict__ out,
                                                       int R, int C) {
  __shared__ float tile[32][33];
  const int tx = threadIdx.x & 31, ty = threadIdx.x >> 5;
  const int c0 = blockIdx.x * 32, r0 = blockIdx.y * 32;
#pragma unroll
  for (int i = 0; i < 32; i += 8)
    tile[ty + i][tx] = in[(size_t)(r0 + ty + i) * C + c0 + tx];
  __syncthreads();
#pragma unroll
  for (int i = 0; i < 32; i += 8)
    out[(size_t)(c0 + ty + i) * R + r0 + tx] = (_Float16)tile[tx][ty + i];
}

// ---------------- GEMM0: 256x256 tile, BK=64, 4-phase K-loop (R8, frozen) -----
// 115 us, MfmaUtil 29%, conflicts 0, FETCH 59 MB. R2/R4/R8 schedule variants
// all land 28-29% -> intra-block schedule is not the limiter at 2 waves/SIMD;
// frozen per rule #10 (no more ceiling-probing from failed attempts).
__global__ __launch_bounds__(512, 2) void gemm256_k(const _Float16* __restrict__ A,
                                                    const _Float16* __restrict__ BT,
                                                    const float* __restrict__ bias,
                                                    _Float16* __restrict__ Qf,
                                                    _Float16* __restrict__ Kf,
                                                    _Float16* __restrict__ VTf) {
  __shared__ _Float16 sA[2][2][128 * 64];  // [buf][half][row*64 + col], 64 KB
  __shared__ _Float16 sB[2][2][128 * 64];  // 64 KB
  const int tid = threadIdx.x;
  const int wave = tid >> 6, lane = tid & 63;
  const int quad = lane >> 4, l16 = lane & 15;
  const int wm = wave >> 2, wn = wave & 3;      // wave grid 2M x 4N
  const int bh = wn >> 1, brb = (wn & 1) * 64;  // B half + row base within half
  const int KD = 1280, NT = 20;                 // 20 K-tiles of 64

  // A-pinned XCD mapping
  const int id = blockIdx.x;
  const int xcd = id & 7;
  const int qq = (id >> 3) & 3;
  const int tn = id >> 5;           // 0..14
  const int tm = xcd * 4 + qq;      // 0..31
  const int m0 = tm * 256, n0 = tn * 256;

  f32x4 acc[8][4] = {};

  // hoisted ds_read bases
  const int b2 = (l16 >> 2) & 1, q3x = quad ^ (l16 & 3);
  const int pg0 = b2 * 4 + q3x;          // kk=0 group
  const int pg1 = (4 - b2 * 4) + q3x;    // kk=1 group
  const _Float16* aB0 = &sA[0][wm][0] + l16 * 64 + pg0 * 8;
  const _Float16* aB1 = &sA[0][wm][0] + l16 * 64 + pg1 * 8;
  const _Float16* bB0 = &sB[0][bh][0] + brb * 64 + l16 * 64 + pg0 * 8;
  const _Float16* bB1 = &sB[0][bh][0] + brb * 64 + l16 * 64 + pg1 * 8;

  auto stageA = [&](int buf, int half, int kt) {
#pragma unroll
    for (int c = 0; c < 2; ++c) {
      const int s = c * 512 + wave * 64 + lane;
      const int row = s >> 3;
      const int lg = (s & 7) ^ (row & 7);
      async16(A + (size_t)(m0 + half * 128 + row) * KD + kt * 64 + lg * 8,
              &sA[buf][half][(size_t)(c * 512 + wave * 64) * 8]);
    }
  };
  auto stageB = [&](int buf, int half, int kt) {
#pragma unroll
    for (int c = 0; c < 2; ++c) {
      const int s = c * 512 + wave * 64 + lane;
      const int row = s >> 3;
      const int lg = (s & 7) ^ (row & 7);
      async16(BT + (size_t)(n0 + half * 128 + row) * KD + kt * 64 + lg * 8,
              &sB[buf][half][(size_t)(c * 512 + wave * 64) * 8]);
    }
  };
  auto ldA = [&](half8* af, int buf, int rh) {
#pragma unroll
    for (int i = 0; i < 4; ++i) {
      af[i * 2 + 0] = *(const half8*)(aB0 + buf * 16384 + rh * 4096 + i * 1024);
      af[i * 2 + 1] = *(const half8*)(aB1 + buf * 16384 + rh * 4096 + i * 1024);
    }
  };
  auto ldB = [&](half8* bf, int buf, int ch) {
#pragma unroll
    for (int j = 0; j < 2; ++j) {
      bf[j * 2 + 0] = *(const half8*)(bB0 + buf * 16384 + ch * 2048 + j * 1024);
      bf[j * 2 + 1] = *(const half8*)(bB1 + buf * 16384 + ch * 2048 + j * 1024);
    }
  };
  auto mmaq = [&](int r, int c, const half8* af, const half8* bf) {
#pragma unroll
    for (int i = 0; i < 4; ++i)
#pragma unroll
      for (int j = 0; j < 2; ++j)
#pragma unroll
        for (int kk = 0; kk < 2; ++kk)
          acc[r * 4 + i][c * 2 + j] =
              MFMA(af[i * 2 + kk], bf[j * 2 + kk], acc[r * 4 + i][c * 2 + j]);
  };

  // prologue: tile0 A+B, tile1 B; vmcnt(4) leaves B(t1)x4 in flight
  stageA(0, 0, 0); stageA(0, 1, 0);
  stageB(0, 0, 0); stageB(0, 1, 0);
  stageB(1, 0, 1); stageB(1, 1, 1);
  asm volatile("s_waitcnt vmcnt(4)" ::: "memory");

  half8 af[8], bf0[4], bf1[4];
#pragma unroll 2
  for (int t = 0; t < NT; ++t) {
    const int buf = t & 1;

    BARE_BAR();
    ldA(af, buf, 0);
    ldB(bf0, buf, 0);
    if (t + 1 < NT) stageA(buf ^ 1, 0, t + 1);
    __builtin_amdgcn_s_setprio(1);
    mmaq(0, 0, af, bf0);
    __builtin_amdgcn_s_setprio(0);

    BARE_BAR();
    ldB(bf1, buf, 1);
    if (t + 1 < NT) stageA(buf ^ 1, 1, t + 1);
    __builtin_amdgcn_s_setprio(1);
    mmaq(0, 1, af, bf1);
    __builtin_amdgcn_s_setprio(0);

    BARE_BAR();
    ldA(af, buf, 1);
    if (t + 2 < NT) stageB(buf, 0, t + 2);
    __builtin_amdgcn_s_setprio(1);
    mmaq(1, 1, af, bf1);
    __builtin_amdgcn_s_setprio(0);

    BARE_BAR();
    if (t + 2 < NT) stageB(buf, 1, t + 2);
    if (t == NT - 2)
      asm volatile("s_waitcnt vmcnt(0)" ::: "memory");  // final drain
    else if (t < NT - 2)
      asm volatile("s_waitcnt vmcnt(4)" ::: "memory");  // counted, never 0
    __builtin_amdgcn_s_setprio(1);
    mmaq(1, 0, af, bf0);
    __builtin_amdgcn_s_setprio(0);
  }

  // scatter epilogue: C row = quad*4+reg, col = l16 within fragment [m89-verified]
#pragma unroll
  for (int ridx = 0; ridx < 8; ++ridx) {
#pragma unroll
    for (int cidx = 0; cidx < 4; ++cidx) {
      const int col = n0 + wn * 64 + cidx * 16 + l16;
      const float bv = bias[col];
      const int rowb = m0 + wm * 128 + ridx * 16 + quad * 4;
      const int which = col / 1280;
      const int rem = col - which * 1280;
      const int h = rem / 80;
      const int kk = rem - h * 80;
#pragma unroll
      for (int r = 0; r < 4; ++r) {
        const float v = acc[ridx][cidx][r] + bv;
        const int mrow = rowb + r;
        const int s = mrow >> 9, l = mrow & 511;
        const int shh = s * 16 + h;
        if (which == 0)
          Qf[((size_t)shh * 512 + l) * 96 + kk] = (_Float16)v;
        else if (which == 1)
          Kf[((size_t)shh * 512 + l) * 96 + kk] = (_Float16)v;
        else
          VTf[((size_t)shh * 80 + kk) * 512 + l] = (_Float16)v;
      }
    }
  }
}

// ---------------- GEMM1 (proj): 128x128 tile, BK=64, 2-phase, 2 blocks/CU -----
// R7 verbatim (won -19.5 us). Frozen as control.
__global__ __launch_bounds__(256) void gemm_k(const _Float16* __restrict__ A,
                                              const _Float16* __restrict__ BT,
                                              const float* __restrict__ bias,
                                              float* __restrict__ Out) {
  __shared__ _Float16 sA[2][128 * 64];  // 32 KB
  __shared__ _Float16 sB[2][128 * 64];  // 32 KB
  const int tid = threadIdx.x;
  const int wave = tid >> 6, lane = tid & 63;
  const int quad = lane >> 4, l16 = lane & 15;
  const int wm = wave >> 1, wn = wave & 1;  // wave grid 2M x 2N, per-wave 64x64
  const int KD = 1280, NT = 20;

  const int m0 = blockIdx.x * 128;
  const int n0 = blockIdx.y * 128;

  f32x4 acc[4][4] = {};

  auto stage = [&](_Float16* dst, const _Float16* src, int rbase, int kt) {
#pragma unroll
    for (int c = 0; c < 4; ++c) {
      const int s = c * 256 + tid;
      const int row = s >> 3;
      const int lg = (s & 7) ^ (row & 7);
      async16(src + (size_t)(rbase + row) * KD + kt * 64 + lg * 8,
              dst + (size_t)(c * 256 + wave * 64) * 8);
    }
  };
  auto ldA = [&](half8* af, const _Float16* hp) {
#pragma unroll
    for (int i = 0; i < 4; ++i)
#pragma unroll
      for (int kk = 0; kk < 2; ++kk) {
        const int lrow = wm * 64 + i * 16 + l16;
        const int pg = (kk * 4 + quad) ^ (l16 & 7);
        af[i * 2 + kk] = *(const half8*)(hp + lrow * 64 + pg * 8);
      }
  };
  auto ldB = [&](half8* bf, const _Float16* hp) {
#pragma unroll
    for (int j = 0; j < 4; ++j)
#pragma unroll
      for (int kk = 0; kk < 2; ++kk) {
        const int brow = wn * 64 + j * 16 + l16;
        const int pg = (kk * 4 + quad) ^ (l16 & 7);
        bf[j * 2 + kk] = *(const half8*)(hp + brow * 64 + pg * 8);
      }
  };

  stage(&sA[0][0], A, m0, 0);
  stage(&sB[0][0], BT, n0, 0);
  asm volatile("s_waitcnt vmcnt(0)" ::: "memory");
  PHB();

  half8 af[8], bf[8];
#pragma unroll 2
  for (int t = 0; t < NT; ++t) {
    const int buf = t & 1;
    if (t + 1 < NT) {
      stage(&sA[buf ^ 1][0], A, m0, t + 1);
      stage(&sB[buf ^ 1][0], BT, n0, t + 1);
    }
    ldA(af, &sA[buf][0]);
    ldB(bf, &sB[buf][0]);
    __builtin_amdgcn_s_setprio(1);
#pragma unroll
    for (int i = 0; i < 4; ++i)
#pragma unroll
      for (int j = 0; j < 4; ++j)
#pragma unroll
        for (int kk = 0; kk < 2; ++kk)
          acc[i][j] = MFMA(af[i * 2 + kk], bf[j * 2 + kk], acc[i][j]);
    __builtin_amdgcn_s_setprio(0);
    if (t + 1 < NT)
      asm volatile("s_waitcnt vmcnt(0)" ::: "memory");  // next tile landed
    PHB();
  }

#pragma unroll
  for (int i = 0; i < 4; ++i) {
#pragma unroll
    for (int j = 0; j < 4; ++j) {
      const int col = n0 + wn * 64 + j * 16 + l16;
      const float bv = bias[col];
      const int rowb = m0 + wm * 64 + i * 16 + quad * 4;
#pragma unroll
      for (int r = 0; r < 4; ++r)
        Out[(size_t)(rowb + r) * 1280 + col] = acc[i][j][r] + bv;
    }
  }
}

// ---------------- RoPE in-place on Qf/Kf + zero the k-pad [80,96), vectorized --
__global__ __launch_bounds__(256) void rope_k(_Float16* __restrict__ Qf,
                                              _Float16* __restrict__ Kf,
                                              const float* __restrict__ cosNK,
                                              const float* __restrict__ sinNK) {
  const int gid = blockIdx.x * 256 + threadIdx.x;  // 2,621,440 = 262144 rows * 10
  const int jt = gid % 10;
  const int row = gid / 10;
  const int qk = row >> 17;
  const int r = row & 131071;      // (s*16+h)*512 + l
  _Float16* buf = qk ? Kf : Qf;
  const int l = r & 511;
  const int s = r >> 13;
  const int t = s * 512 + l;
  const size_t base = (size_t)r * 96;
  const int j0 = jt * 4;

  half4v v1 = *(const half4v*)(buf + base + j0);
  half4v v2 = *(const half4v*)(buf + base + 40 + j0);
  f32x4 c1 = *(const f32x4*)(cosNK + (size_t)t * 80 + j0);
  f32x4 s1 = *(const f32x4*)(sinNK + (size_t)t * 80 + j0);
  f32x4 c2 = *(const f32x4*)(cosNK + (size_t)t * 80 + 40 + j0);
  f32x4 s2 = *(const f32x4*)(sinNK + (size_t)t * 80 + 40 + j0);
  half4v o1, o2;
#pragma unroll
  for (int e = 0; e < 4; ++e) {
    const float a = (float)v1[e], b = (float)v2[e];
    o1[e] = (_Float16)(a * c1[e] - b * s1[e]);
    o2[e] = (_Float16)(b * c2[e] + a * s2[e]);
  }
  *(half4v*)(buf + base + j0) = o1;
  *(half4v*)(buf + base + 40 + j0) = o2;
  if (jt < 2) {  // zero pad kk = 80..95 (two half8 stores)
    half8 z = {};
    *(half8*)(buf + base + 80 + jt * 8) = z;
  }
}

// ---------------- flash attention (S^T form, no-max softmax, sum via ones) ----
// R9: double-buffered K/V staging (T14/T3-minimum). Old structure exposed the
// full DMA latency serially each kc: sync -> 25 DMA -> vmcnt(0) -> sync ->
// compute. Now: stage kc+1 into buf^1 BEFORE compute of buf; trailing
// vmcnt(0) (no-op by then) + ONE __syncthreads per kc (was two). Ones rows
// moved to a static region so V buffers are 80x72. LDS 70.4 KB -> 2 blk/CU.
// Race audit: buf^1's last reads were consumed by MFMA (auto-lgkm) before
// the prior barrier -> every DMA into buf^1 issues after all reads complete;
// each wave's vmcnt(0) precedes its barrier arrival -> buf data visible to
// all waves after the barrier. sP rows wave-private (no barrier needed).
__global__ __launch_bounds__(256) void attn_k(const _Float16* __restrict__ Qf,
                                              const _Float16* __restrict__ Kf,
                                              const _Float16* __restrict__ VTf,
                                              _Float16* __restrict__ attnA) {
  __shared__ _Float16 sP[128 * 72];      // 18.4 KB, P tile (stride 72)
  __shared__ _Float16 sK[2][64 * 104];   // 26.6 KB, K dbuf (stride 104)
  __shared__ _Float16 sV[2][80 * 72];    // 23.0 KB, V^T dbuf (stride 72)
  __shared__ _Float16 sOnes[16 * 72];    //  2.3 KB, static ones rows
  const int tid = threadIdx.x;
  const int wave = tid >> 6, lane = tid & 63;
  const int quad = lane >> 4, l16 = lane & 15;
  const int shh = blockIdx.x;  // s*16+h
  const int qt = blockIdx.y;   // 0..3
  const int h = shh & 15;
  const int s = shh >> 4;

  const _Float16* Qb = Qf + ((size_t)shh * 512 + qt * 128) * 96;
  const _Float16* Kb0 = Kf + (size_t)shh * 512 * 96;
  const _Float16* Vb0 = VTf + (size_t)shh * 80 * 512;

  // Q fragments straight from global (rows are lane-exact), pre-scaled
  const _Float16 c1h = (_Float16)(ATT_SCALE * LOG2E);
  half8 qf[2][3];
#pragma unroll
  for (int rt = 0; rt < 2; ++rt)
#pragma unroll
    for (int ks = 0; ks < 3; ++ks) {
      half8 t = *(const half8*)(Qb + (size_t)(wave * 32 + rt * 16 + l16) * 96 +
                                ks * 32 + quad * 8);
#pragma unroll
      for (int e = 0; e < 8; ++e) t[e] *= c1h;
      qf[rt][ks] = t;
    }

  // stage K tile (stride 104 halves, masked 13-chunk DMA) + V^T tile
  // (stride 72 halves, masked 12-chunk DMA) for kc into buffer b
  auto stageKV = [&](int b, int kc) {
    const _Float16* Kb = Kb0 + (size_t)kc * 64 * 96;
#pragma unroll
    for (int c = 0; c < 4; ++c) {
      const int j = wave + 4 * c;
      if (j < 13) {
        const int off = j * 1024 + lane * 16;  // LDS byte offset
        const int krow = off / 208;
        const int kcol = off - krow * 208;     // bytes within padded row
        if (kcol < 192)
          async16(Kb + (size_t)krow * 96 + (kcol >> 1), &sK[b][j * 512]);
      }
    }
#pragma unroll
    for (int c = 0; c < 3; ++c) {
      const int j = wave + 4 * c;
      const int off = j * 1024 + lane * 16;
      const int vrow = off / 144;
      const int colb = off - vrow * 144;
      if (vrow < 80 && colb < 128)
        async16(Vb0 + (size_t)vrow * 512 + kc * 64 + (colb >> 1), &sV[b][j * 512]);
    }
  };

  // ones rows (static; written once, read every kc by ft=5)
  for (int idx = tid; idx < 16 * 72; idx += 256) sOnes[idx] = (_Float16)1.f;

  // prologue: kc=0 into buf0
  stageKV(0, 0);
  asm volatile("s_waitcnt vmcnt(0)" ::: "memory");
  __syncthreads();

  f32x4 o[2][6] = {};  // ft 0..4: output features; ft 5: row sum

#pragma unroll 2
  for (int kc = 0; kc < 8; ++kc) {
    const int buf = kc & 1;
    const _Float16* sKb = &sK[buf][0];
    const _Float16* sVb = &sV[buf][0];

    // issue next tile's DMA first — latency hides under this tile's compute
    if (kc < 7) stageKV(buf ^ 1, kc + 1);

    // S^T = K Q^T (operand swap): lane holds S[q=l16][k=mt*16+quad*4+r]
    f32x4 sacc[2][4] = {};  // [rt][mt]
#pragma unroll
    for (int mt = 0; mt < 4; ++mt) {
#pragma unroll
      for (int ks = 0; ks < 3; ++ks) {
        half8 kb = *(const half8*)&sKb[(mt * 16 + l16) * 104 + ks * 32 + quad * 8];
        sacc[0][mt] = MFMA(kb, qf[0][ks], sacc[0][mt]);
        sacc[1][mt] = MFMA(kb, qf[1][ks], sacc[1][mt]);
      }
    }

    // p = exp2(s), packed pairs (consecutive k!), one b64 store per (rt,mt)
#pragma unroll
    for (int rt = 0; rt < 2; ++rt) {
#pragma unroll
      for (int mt = 0; mt < 4; ++mt) {
        union { fp16x2 h2[2]; half4v h4; } u;
        u.h2[0] = __builtin_amdgcn_cvt_pkrtz(
            __builtin_amdgcn_exp2f(sacc[rt][mt][0]),
            __builtin_amdgcn_exp2f(sacc[rt][mt][1]));
        u.h2[1] = __builtin_amdgcn_cvt_pkrtz(
            __builtin_amdgcn_exp2f(sacc[rt][mt][2]),
            __builtin_amdgcn_exp2f(sacc[rt][mt][3]));
        *(half4v*)&sP[(wave * 32 + rt * 16 + l16) * 72 + mt * 16 + quad * 4] = u.h4;
      }
    }
    // sP rows are wave-private: per-wave LDS ordering suffices, no barrier

    // O += P V  (ft=5 accumulates the row sum via the static ones rows)
#pragma unroll
    for (int ks = 0; ks < 2; ++ks) {
      half8 pa[2];
      pa[0] = *(const half8*)&sP[(wave * 32 + 0 + l16) * 72 + ks * 32 + quad * 8];
      pa[1] = *(const half8*)&sP[(wave * 32 + 16 + l16) * 72 + ks * 32 + quad * 8];
#pragma unroll
      for (int ft = 0; ft < 6; ++ft) {
        half8 vb = (ft < 5)
            ? *(const half8*)&sVb[(ft * 16 + l16) * 72 + ks * 32 + quad * 8]
            : *(const half8*)&sOnes[l16 * 72 + ks * 32 + quad * 8];
        o[0][ft] = MFMA(pa[0], vb, o[0][ft]);
        o[1][ft] = MFMA(pa[1], vb, o[1][ft]);
      }
    }

    // next tile landed (DMA issued ~full compute phase ago) + buffer handoff
    if (kc < 7) {
      asm volatile("s_waitcnt vmcnt(0)" ::: "memory");
      __syncthreads();
    }
  }

  // epilogue: divide by row sum, store fp16 into attnA [token][h*80+f]
#pragma unroll
  for (int rt = 0; rt < 2; ++rt) {
#pragma unroll
    for (int r = 0; r < 4; ++r) {
      const float inv = 1.0f / o[rt][5][r];
      const int token = s * 512 + qt * 128 + wave * 32 + rt * 16 + quad * 4 + r;
#pragma unroll
      for (int ft = 0; ft < 5; ++ft)
        attnA[(size_t)token * 1280 + h * 80 + ft * 16 + l16] =
            (_Float16)(o[rt][ft][r] * inv);
    }
  }
}

extern "C" void kernel_launch(void* const* d_in, const int* in_sizes, int n_in,
                              void* d_out, int out_size, void* d_ws, size_t ws_size,
                              hipStream_t stream) {
  (void)in_sizes; (void)n_in; (void)out_size; (void)ws_size;
  const float* hidden = (const float*)d_in[0];
  const float* cosNK = (const float*)d_in[2];
  const float* sinNK = (const float*)d_in[3];
  const float* qkv_w = (const float*)d_in[4];
  const float* qkv_b = (const float*)d_in[5];
  const float* proj_w = (const float*)d_in[6];
  const float* proj_b = (const float*)d_in[7];
  float* out = (float*)d_out;

  char* ws = (char*)d_ws;
  _Float16* hA    = (_Float16*)(ws);                   // 8192x1280        20971520 B
  _Float16* wT    = (_Float16*)(ws + 20971520);        // 3840x1280         9830400 B
  _Float16* projT = (_Float16*)(ws + 30801920);        // 1280x1280         3276800 B
  _Float16* Qf    = (_Float16*)(ws + 34078720);        // 256x512x96       25165824 B
  _Float16* Kf    = (_Float16*)(ws + 59244544);        // 256x512x96       25165824 B
  _Float16* VTf   = (_Float16*)(ws + 84410368);        // 256x80x512       20971520 B
  _Float16* attnA = (_Float16*)(ws + 105381888);       // 8192x1280        20971520 B

  cvt_k<<<10240, 256, 0, stream>>>(hidden, hA, 2621440);
  transpose_cvt_k<<<dim3(120, 40), 256, 0, stream>>>(qkv_w, wT, 1280, 3840);
  transpose_cvt_k<<<dim3(40, 40), 256, 0, stream>>>(proj_w, projT, 1280, 1280);
  gemm256_k<<<480, 512, 0, stream>>>(hA, wT, qkv_b, Qf, Kf, VTf);
  rope_k<<<10240, 256, 0, stream>>>(Qf, Kf, cosNK, sinNK);
  attn_k<<<dim3(256, 4), 256, 0, stream>>>(Qf, Kf, VTf, attnA);
  gemm_k<<<dim3(64, 10), 256, 0, stream>>>(attnA, projT, proj_b, out);
}

// Round 10
// 336.515 us; speedup vs baseline: 1.0149x; 1.0129x over previous
//
#include <hip/hip_runtime.h>

// Problem constants (fixed shape)
// N=8192 tokens, D=1280, H=16 heads, K=80 head dim (pad 96), S=16 segs, L=512
#define LOG2E 1.44269504088896340736f
#define ATT_SCALE 0.11180339887498949f  // 80^-0.5

typedef _Float16 half8 __attribute__((ext_vector_type(8)));
typedef _Float16 half4v __attribute__((ext_vector_type(4)));
typedef __fp16 fp16x2 __attribute__((ext_vector_type(2)));
typedef float f32x4 __attribute__((ext_vector_type(4)));

#define MFMA(a, b, c) __builtin_amdgcn_mfma_f32_16x16x32_f16((a), (b), (c), 0, 0, 0)

__device__ __forceinline__ void async16(const _Float16* g, _Float16* l) {
  __builtin_amdgcn_global_load_lds(
      (const __attribute__((address_space(1))) unsigned int*)g,
      (__attribute__((address_space(3))) unsigned int*)l,
      16, 0, 0);
}

#define FENCE() asm volatile("" ::: "memory")
// fenced barrier (used by gemm_k, proven R7 structure)
#define PHB()                                   \
  do {                                          \
    FENCE();                                    \
    __builtin_amdgcn_s_barrier();               \
    FENCE();                                    \
  } while (0)
// bare barrier (gemm256, R8 — equal to R4 within noise; kept)
#define BARE_BAR() __builtin_amdgcn_s_barrier()

// ---------------- prep: fused cvt(hidden) + transpose(qkv_w) + transpose(proj_w)
// R10: the three preprocessing kernels are independent and memory-bound;
// fusing removes 2 kernel boundaries (launch-gap theory: ~95 us of the total
// lives between dispatches) and overlaps their memory streams across CUs.
// Block ranges: [0,10240) cvt; [10240,15040) qkv_w transpose (120x40);
// [15040,16640) proj_w transpose (40x40). Branch is block-uniform.
__global__ __launch_bounds__(256) void prep_k(const float* __restrict__ hidden,
                                              _Float16* __restrict__ hA,
                                              const float* __restrict__ qkv_w,
                                              _Float16* __restrict__ wT,
                                              const float* __restrict__ proj_w,
                                              _Float16* __restrict__ projT) {
  __shared__ float tile[32][33];
  const int b = blockIdx.x;
  if (b < 10240) {
    // cvt: 10240*256 == 2,621,440 float4s exactly (no bound check needed)
    const int i = b * 256 + threadIdx.x;
    f32x4 v = ((const f32x4*)hidden)[i];
    half4v hv;
    hv[0] = (_Float16)v[0]; hv[1] = (_Float16)v[1];
    hv[2] = (_Float16)v[2]; hv[3] = (_Float16)v[3];
    ((half4v*)hA)[i] = hv;
    return;
  }
  // transpose+cvt: in R x C fp32 -> out C x R fp16
  const float* in;
  _Float16* out;
  int R, C, bx, by;
  if (b < 15040) {
    const int i = b - 10240;
    in = qkv_w; out = wT; R = 1280; C = 3840;
    bx = i % 120; by = i / 120;
  } else {
    const int i = b - 15040;
    in = proj_w; out = projT; R = 1280; C = 1280;
    bx = i % 40; by = i / 40;
  }
  const int tx = threadIdx.x & 31, ty = threadIdx.x >> 5;
  const int c0 = bx * 32, r0 = by * 32;
#pragma unroll
  for (int i = 0; i < 32; i += 8)
    tile[ty + i][tx] = in[(size_t)(r0 + ty + i) * C + c0 + tx];
  __syncthreads();
#pragma unroll
  for (int i = 0; i < 32; i += 8)
    out[(size_t)(c0 + ty + i) * R + r0 + tx] = (_Float16)tile[tx][ty + i];
}

// ---------------- GEMM0: 256x256 tile, BK=64, 4-phase K-loop (R8, frozen) -----
// 115 us, MfmaUtil 29%, conflicts 0, FETCH 59 MB. R2/R4/R8 schedule variants
// all land 28-29% -> intra-block schedule is not the limiter at 2 waves/SIMD;
// frozen per rule #10 (no more ceiling-probing from failed attempts).
__global__ __launch_bounds__(512, 2) void gemm256_k(const _Float16* __restrict__ A,
                                                    const _Float16* __restrict__ BT,
                                                    const float* __restrict__ bias,
                                                    _Float16* __restrict__ Qf,
                                                    _Float16* __restrict__ Kf,
                                                    _Float16* __restrict__ VTf) {
  __shared__ _Float16 sA[2][2][128 * 64];  // [buf][half][row*64 + col], 64 KB
  __shared__ _Float16 sB[2][2][128 * 64];  // 64 KB
  const int tid = threadIdx.x;
  const int wave = tid >> 6, lane = tid & 63;
  const int quad = lane >> 4, l16 = lane & 15;
  const int wm = wave >> 2, wn = wave & 3;      // wave grid 2M x 4N
  const int bh = wn >> 1, brb = (wn & 1) * 64;  // B half + row base within half
  const int KD = 1280, NT = 20;                 // 20 K-tiles of 64

  // A-pinned XCD mapping
  const int id = blockIdx.x;
  const int xcd = id & 7;
  const int qq = (id >> 3) & 3;
  const int tn = id >> 5;           // 0..14
  const int tm = xcd * 4 + qq;      // 0..31
  const int m0 = tm * 256, n0 = tn * 256;

  f32x4 acc[8][4] = {};

  // hoisted ds_read bases
  const int b2 = (l16 >> 2) & 1, q3x = quad ^ (l16 & 3);
  const int pg0 = b2 * 4 + q3x;          // kk=0 group
  const int pg1 = (4 - b2 * 4) + q3x;    // kk=1 group
  const _Float16* aB0 = &sA[0][wm][0] + l16 * 64 + pg0 * 8;
  const _Float16* aB1 = &sA[0][wm][0] + l16 * 64 + pg1 * 8;
  const _Float16* bB0 = &sB[0][bh][0] + brb * 64 + l16 * 64 + pg0 * 8;
  const _Float16* bB1 = &sB[0][bh][0] + brb * 64 + l16 * 64 + pg1 * 8;

  auto stageA = [&](int buf, int half, int kt) {
#pragma unroll
    for (int c = 0; c < 2; ++c) {
      const int s = c * 512 + wave * 64 + lane;
      const int row = s >> 3;
      const int lg = (s & 7) ^ (row & 7);
      async16(A + (size_t)(m0 + half * 128 + row) * KD + kt * 64 + lg * 8,
              &sA[buf][half][(size_t)(c * 512 + wave * 64) * 8]);
    }
  };
  auto stageB = [&](int buf, int half, int kt) {
#pragma unroll
    for (int c = 0; c < 2; ++c) {
      const int s = c * 512 + wave * 64 + lane;
      const int row = s >> 3;
      const int lg = (s & 7) ^ (row & 7);
      async16(BT + (size_t)(n0 + half * 128 + row) * KD + kt * 64 + lg * 8,
              &sB[buf][half][(size_t)(c * 512 + wave * 64) * 8]);
    }
  };
  auto ldA = [&](half8* af, int buf, int rh) {
#pragma unroll
    for (int i = 0; i < 4; ++i) {
      af[i * 2 + 0] = *(const half8*)(aB0 + buf * 16384 + rh * 4096 + i * 1024);
      af[i * 2 + 1] = *(const half8*)(aB1 + buf * 16384 + rh * 4096 + i * 1024);
    }
  };
  auto ldB = [&](half8* bf, int buf, int ch) {
#pragma unroll
    for (int j = 0; j < 2; ++j) {
      bf[j * 2 + 0] = *(const half8*)(bB0 + buf * 16384 + ch * 2048 + j * 1024);
      bf[j * 2 + 1] = *(const half8*)(bB1 + buf * 16384 + ch * 2048 + j * 1024);
    }
  };
  auto mmaq = [&](int r, int c, const half8* af, const half8* bf) {
#pragma unroll
    for (int i = 0; i < 4; ++i)
#pragma unroll
      for (int j = 0; j < 2; ++j)
#pragma unroll
        for (int kk = 0; kk < 2; ++kk)
          acc[r * 4 + i][c * 2 + j] =
              MFMA(af[i * 2 + kk], bf[j * 2 + kk], acc[r * 4 + i][c * 2 + j]);
  };

  // prologue: tile0 A+B, tile1 B; vmcnt(4) leaves B(t1)x4 in flight
  stageA(0, 0, 0); stageA(0, 1, 0);
  stageB(0, 0, 0); stageB(0, 1, 0);
  stageB(1, 0, 1); stageB(1, 1, 1);
  asm volatile("s_waitcnt vmcnt(4)" ::: "memory");

  half8 af[8], bf0[4], bf1[4];
#pragma unroll 2
  for (int t = 0; t < NT; ++t) {
    const int buf = t & 1;

    BARE_BAR();
    ldA(af, buf, 0);
    ldB(bf0, buf, 0);
    if (t + 1 < NT) stageA(buf ^ 1, 0, t + 1);
    __builtin_amdgcn_s_setprio(1);
    mmaq(0, 0, af, bf0);
    __builtin_amdgcn_s_setprio(0);

    BARE_BAR();
    ldB(bf1, buf, 1);
    if (t + 1 < NT) stageA(buf ^ 1, 1, t + 1);
    __builtin_amdgcn_s_setprio(1);
    mmaq(0, 1, af, bf1);
    __builtin_amdgcn_s_setprio(0);

    BARE_BAR();
    ldA(af, buf, 1);
    if (t + 2 < NT) stageB(buf, 0, t + 2);
    __builtin_amdgcn_s_setprio(1);
    mmaq(1, 1, af, bf1);
    __builtin_amdgcn_s_setprio(0);

    BARE_BAR();
    if (t + 2 < NT) stageB(buf, 1, t + 2);
    if (t == NT - 2)
      asm volatile("s_waitcnt vmcnt(0)" ::: "memory");  // final drain
    else if (t < NT - 2)
      asm volatile("s_waitcnt vmcnt(4)" ::: "memory");  // counted, never 0
    __builtin_amdgcn_s_setprio(1);
    mmaq(1, 0, af, bf0);
    __builtin_amdgcn_s_setprio(0);
  }

  // scatter epilogue: C row = quad*4+reg, col = l16 within fragment [m89-verified]
#pragma unroll
  for (int ridx = 0; ridx < 8; ++ridx) {
#pragma unroll
    for (int cidx = 0; cidx < 4; ++cidx) {
      const int col = n0 + wn * 64 + cidx * 16 + l16;
      const float bv = bias[col];
      const int rowb = m0 + wm * 128 + ridx * 16 + quad * 4;
      const int which = col / 1280;
      const int rem = col - which * 1280;
      const int h = rem / 80;
      const int kk = rem - h * 80;
#pragma unroll
      for (int r = 0; r < 4; ++r) {
        const float v = acc[ridx][cidx][r] + bv;
        const int mrow = rowb + r;
        const int s = mrow >> 9, l = mrow & 511;
        const int shh = s * 16 + h;
        if (which == 0)
          Qf[((size_t)shh * 512 + l) * 96 + kk] = (_Float16)v;
        else if (which == 1)
          Kf[((size_t)shh * 512 + l) * 96 + kk] = (_Float16)v;
        else
          VTf[((size_t)shh * 80 + kk) * 512 + l] = (_Float16)v;
      }
    }
  }
}

// ---------------- GEMM1 (proj): 128x128 tile, BK=64, 2-phase, 2 blocks/CU -----
// R7 verbatim (won -19.5 us). Frozen as control.
__global__ __launch_bounds__(256) void gemm_k(const _Float16* __restrict__ A,
                                              const _Float16* __restrict__ BT,
                                              const float* __restrict__ bias,
                                              float* __restrict__ Out) {
  __shared__ _Float16 sA[2][128 * 64];  // 32 KB
  __shared__ _Float16 sB[2][128 * 64];  // 32 KB
  const int tid = threadIdx.x;
  const int wave = tid >> 6, lane = tid & 63;
  const int quad = lane >> 4, l16 = lane & 15;
  const int wm = wave >> 1, wn = wave & 1;  // wave grid 2M x 2N, per-wave 64x64
  const int KD = 1280, NT = 20;

  const int m0 = blockIdx.x * 128;
  const int n0 = blockIdx.y * 128;

  f32x4 acc[4][4] = {};

  auto stage = [&](_Float16* dst, const _Float16* src, int rbase, int kt) {
#pragma unroll
    for (int c = 0; c < 4; ++c) {
      const int s = c * 256 + tid;
      const int row = s >> 3;
      const int lg = (s & 7) ^ (row & 7);
      async16(src + (size_t)(rbase + row) * KD + kt * 64 + lg * 8,
              dst + (size_t)(c * 256 + wave * 64) * 8);
    }
  };
  auto ldA = [&](half8* af, const _Float16* hp) {
#pragma unroll
    for (int i = 0; i < 4; ++i)
#pragma unroll
      for (int kk = 0; kk < 2; ++kk) {
        const int lrow = wm * 64 + i * 16 + l16;
        const int pg = (kk * 4 + quad) ^ (l16 & 7);
        af[i * 2 + kk] = *(const half8*)(hp + lrow * 64 + pg * 8);
      }
  };
  auto ldB = [&](half8* bf, const _Float16* hp) {
#pragma unroll
    for (int j = 0; j < 4; ++j)
#pragma unroll
      for (int kk = 0; kk < 2; ++kk) {
        const int brow = wn * 64 + j * 16 + l16;
        const int pg = (kk * 4 + quad) ^ (l16 & 7);
        bf[j * 2 + kk] = *(const half8*)(hp + brow * 64 + pg * 8);
      }
  };

  stage(&sA[0][0], A, m0, 0);
  stage(&sB[0][0], BT, n0, 0);
  asm volatile("s_waitcnt vmcnt(0)" ::: "memory");
  PHB();

  half8 af[8], bf[8];
#pragma unroll 2
  for (int t = 0; t < NT; ++t) {
    const int buf = t & 1;
    if (t + 1 < NT) {
      stage(&sA[buf ^ 1][0], A, m0, t + 1);
      stage(&sB[buf ^ 1][0], BT, n0, t + 1);
    }
    ldA(af, &sA[buf][0]);
    ldB(bf, &sB[buf][0]);
    __builtin_amdgcn_s_setprio(1);
#pragma unroll
    for (int i = 0; i < 4; ++i)
#pragma unroll
      for (int j = 0; j < 4; ++j)
#pragma unroll
        for (int kk = 0; kk < 2; ++kk)
          acc[i][j] = MFMA(af[i * 2 + kk], bf[j * 2 + kk], acc[i][j]);
    __builtin_amdgcn_s_setprio(0);
    if (t + 1 < NT)
      asm volatile("s_waitcnt vmcnt(0)" ::: "memory");  // next tile landed
    PHB();
  }

#pragma unroll
  for (int i = 0; i < 4; ++i) {
#pragma unroll
    for (int j = 0; j < 4; ++j) {
      const int col = n0 + wn * 64 + j * 16 + l16;
      const float bv = bias[col];
      const int rowb = m0 + wm * 64 + i * 16 + quad * 4;
#pragma unroll
      for (int r = 0; r < 4; ++r)
        Out[(size_t)(rowb + r) * 1280 + col] = acc[i][j][r] + bv;
    }
  }
}

// ---------------- RoPE in-place on Qf/Kf + zero the k-pad [80,96), vectorized --
__global__ __launch_bounds__(256) void rope_k(_Float16* __restrict__ Qf,
                                              _Float16* __restrict__ Kf,
                                              const float* __restrict__ cosNK,
                                              const float* __restrict__ sinNK) {
  const int gid = blockIdx.x * 256 + threadIdx.x;  // 2,621,440 = 262144 rows * 10
  const int jt = gid % 10;
  const int row = gid / 10;
  const int qk = row >> 17;
  const int r = row & 131071;      // (s*16+h)*512 + l
  _Float16* buf = qk ? Kf : Qf;
  const int l = r & 511;
  const int s = r >> 13;
  const int t = s * 512 + l;
  const size_t base = (size_t)r * 96;
  const int j0 = jt * 4;

  half4v v1 = *(const half4v*)(buf + base + j0);
  half4v v2 = *(const half4v*)(buf + base + 40 + j0);
  f32x4 c1 = *(const f32x4*)(cosNK + (size_t)t * 80 + j0);
  f32x4 s1 = *(const f32x4*)(sinNK + (size_t)t * 80 + j0);
  f32x4 c2 = *(const f32x4*)(cosNK + (size_t)t * 80 + 40 + j0);
  f32x4 s2 = *(const f32x4*)(sinNK + (size_t)t * 80 + 40 + j0);
  half4v o1, o2;
#pragma unroll
  for (int e = 0; e < 4; ++e) {
    const float a = (float)v1[e], b = (float)v2[e];
    o1[e] = (_Float16)(a * c1[e] - b * s1[e]);
    o2[e] = (_Float16)(b * c2[e] + a * s2[e]);
  }
  *(half4v*)(buf + base + j0) = o1;
  *(half4v*)(buf + base + 40 + j0) = o2;
  if (jt < 2) {  // zero pad kk = 80..95 (two half8 stores)
    half8 z = {};
    *(half8*)(buf + base + 80 + jt * 8) = z;
  }
}

// ---------------- flash attention (S^T form, no-max softmax, sum via ones) ----
// R9 double-buffered staging (kept: neutral but structurally cleaner; one
// sync per kc). Frozen as control this round.
__global__ __launch_bounds__(256) void attn_k(const _Float16* __restrict__ Qf,
                                              const _Float16* __restrict__ Kf,
                                              const _Float16* __restrict__ VTf,
                                              _Float16* __restrict__ attnA) {
  __shared__ _Float16 sP[128 * 72];      // 18.4 KB, P tile (stride 72)
  __shared__ _Float16 sK[2][64 * 104];   // 26.6 KB, K dbuf (stride 104)
  __shared__ _Float16 sV[2][80 * 72];    // 23.0 KB, V^T dbuf (stride 72)
  __shared__ _Float16 sOnes[16 * 72];    //  2.3 KB, static ones rows
  const int tid = threadIdx.x;
  const int wave = tid >> 6, lane = tid & 63;
  const int quad = lane >> 4, l16 = lane & 15;
  const int shh = blockIdx.x;  // s*16+h
  const int qt = blockIdx.y;   // 0..3
  const int h = shh & 15;
  const int s = shh >> 4;

  const _Float16* Qb = Qf + ((size_t)shh * 512 + qt * 128) * 96;
  const _Float16* Kb0 = Kf + (size_t)shh * 512 * 96;
  const _Float16* Vb0 = VTf + (size_t)shh * 80 * 512;

  // Q fragments straight from global (rows are lane-exact), pre-scaled
  const _Float16 c1h = (_Float16)(ATT_SCALE * LOG2E);
  half8 qf[2][3];
#pragma unroll
  for (int rt = 0; rt < 2; ++rt)
#pragma unroll
    for (int ks = 0; ks < 3; ++ks) {
      half8 t = *(const half8*)(Qb + (size_t)(wave * 32 + rt * 16 + l16) * 96 +
                                ks * 32 + quad * 8);
#pragma unroll
      for (int e = 0; e < 8; ++e) t[e] *= c1h;
      qf[rt][ks] = t;
    }

  // stage K tile (stride 104 halves, masked 13-chunk DMA) + V^T tile
  // (stride 72 halves, masked 12-chunk DMA) for kc into buffer b
  auto stageKV = [&](int b, int kc) {
    const _Float16* Kb = Kb0 + (size_t)kc * 64 * 96;
#pragma unroll
    for (int c = 0; c < 4; ++c) {
      const int j = wave + 4 * c;
      if (j < 13) {
        const int off = j * 1024 + lane * 16;  // LDS byte offset
        const int krow = off / 208;
        const int kcol = off - krow * 208;     // bytes within padded row
        if (kcol < 192)
          async16(Kb + (size_t)krow * 96 + (kcol >> 1), &sK[b][j * 512]);
      }
    }
#pragma unroll
    for (int c = 0; c < 3; ++c) {
      const int j = wave + 4 * c;
      const int off = j * 1024 + lane * 16;
      const int vrow = off / 144;
      const int colb = off - vrow * 144;
      if (vrow < 80 && colb < 128)
        async16(Vb0 + (size_t)vrow * 512 + kc * 64 + (colb >> 1), &sV[b][j * 512]);
    }
  };

  // ones rows (static; written once, read every kc by ft=5)
  for (int idx = tid; idx < 16 * 72; idx += 256) sOnes[idx] = (_Float16)1.f;

  // prologue: kc=0 into buf0
  stageKV(0, 0);
  asm volatile("s_waitcnt vmcnt(0)" ::: "memory");
  __syncthreads();

  f32x4 o[2][6] = {};  // ft 0..4: output features; ft 5: row sum

#pragma unroll 2
  for (int kc = 0; kc < 8; ++kc) {
    const int buf = kc & 1;
    const _Float16* sKb = &sK[buf][0];
    const _Float16* sVb = &sV[buf][0];

    // issue next tile's DMA first — latency hides under this tile's compute
    if (kc < 7) stageKV(buf ^ 1, kc + 1);

    // S^T = K Q^T (operand swap): lane holds S[q=l16][k=mt*16+quad*4+r]
    f32x4 sacc[2][4] = {};  // [rt][mt]
#pragma unroll
    for (int mt = 0; mt < 4; ++mt) {
#pragma unroll
      for (int ks = 0; ks < 3; ++ks) {
        half8 kb = *(const half8*)&sKb[(mt * 16 + l16) * 104 + ks * 32 + quad * 8];
        sacc[0][mt] = MFMA(kb, qf[0][ks], sacc[0][mt]);
        sacc[1][mt] = MFMA(kb, qf[1][ks], sacc[1][mt]);
      }
    }

    // p = exp2(s), packed pairs (consecutive k!), one b64 store per (rt,mt)
#pragma unroll
    for (int rt = 0; rt < 2; ++rt) {
#pragma unroll
      for (int mt = 0; mt < 4; ++mt) {
        union { fp16x2 h2[2]; half4v h4; } u;
        u.h2[0] = __builtin_amdgcn_cvt_pkrtz(
            __builtin_amdgcn_exp2f(sacc[rt][mt][0]),
            __builtin_amdgcn_exp2f(sacc[rt][mt][1]));
        u.h2[1] = __builtin_amdgcn_cvt_pkrtz(
            __builtin_amdgcn_exp2f(sacc[rt][mt][2]),
            __builtin_amdgcn_exp2f(sacc[rt][mt][3]));
        *(half4v*)&sP[(wave * 32 + rt * 16 + l16) * 72 + mt * 16 + quad * 4] = u.h4;
      }
    }
    // sP rows are wave-private: per-wave LDS ordering suffices, no barrier

    // O += P V  (ft=5 accumulates the row sum via the static ones rows)
#pragma unroll
    for (int ks = 0; ks < 2; ++ks) {
      half8 pa[2];
      pa[0] = *(const half8*)&sP[(wave * 32 + 0 + l16) * 72 + ks * 32 + quad * 8];
      pa[1] = *(const half8*)&sP[(wave * 32 + 16 + l16) * 72 + ks * 32 + quad * 8];
#pragma unroll
      for (int ft = 0; ft < 6; ++ft) {
        half8 vb = (ft < 5)
            ? *(const half8*)&sVb[(ft * 16 + l16) * 72 + ks * 32 + quad * 8]
            : *(const half8*)&sOnes[l16 * 72 + ks * 32 + quad * 8];
        o[0][ft] = MFMA(pa[0], vb, o[0][ft]);
        o[1][ft] = MFMA(pa[1], vb, o[1][ft]);
      }
    }

    // next tile landed (DMA issued ~full compute phase ago) + buffer handoff
    if (kc < 7) {
      asm volatile("s_waitcnt vmcnt(0)" ::: "memory");
      __syncthreads();
    }
  }

  // epilogue: divide by row sum, store fp16 into attnA [token][h*80+f]
#pragma unroll
  for (int rt = 0; rt < 2; ++rt) {
#pragma unroll
    for (int r = 0; r < 4; ++r) {
      const float inv = 1.0f / o[rt][5][r];
      const int token = s * 512 + qt * 128 + wave * 32 + rt * 16 + quad * 4 + r;
#pragma unroll
      for (int ft = 0; ft < 5; ++ft)
        attnA[(size_t)token * 1280 + h * 80 + ft * 16 + l16] =
            (_Float16)(o[rt][ft][r] * inv);
    }
  }
}

extern "C" void kernel_launch(void* const* d_in, const int* in_sizes, int n_in,
                              void* d_out, int out_size, void* d_ws, size_t ws_size,
                              hipStream_t stream) {
  (void)in_sizes; (void)n_in; (void)out_size; (void)ws_size;
  const float* hidden = (const float*)d_in[0];
  const float* cosNK = (const float*)d_in[2];
  const float* sinNK = (const float*)d_in[3];
  const float* qkv_w = (const float*)d_in[4];
  const float* qkv_b = (const float*)d_in[5];
  const float* proj_w = (const float*)d_in[6];
  const float* proj_b = (const float*)d_in[7];
  float* out = (float*)d_out;

  char* ws = (char*)d_ws;
  _Float16* hA    = (_Float16*)(ws);                   // 8192x1280        20971520 B
  _Float16* wT    = (_Float16*)(ws + 20971520);        // 3840x1280         9830400 B
  _Float16* projT = (_Float16*)(ws + 30801920);        // 1280x1280         3276800 B
  _Float16* Qf    = (_Float16*)(ws + 34078720);        // 256x512x96       25165824 B
  _Float16* Kf    = (_Float16*)(ws + 59244544);        // 256x512x96       25165824 B
  _Float16* VTf   = (_Float16*)(ws + 84410368);        // 256x80x512       20971520 B
  _Float16* attnA = (_Float16*)(ws + 105381888);       // 8192x1280        20971520 B

  prep_k<<<16640, 256, 0, stream>>>(hidden, hA, qkv_w, wT, proj_w, projT);
  gemm256_k<<<480, 512, 0, stream>>>(hA, wT, qkv_b, Qf, Kf, VTf);
  rope_k<<<10240, 256, 0, stream>>>(Qf, Kf, cosNK, sinNK);
  attn_k<<<dim3(256, 4), 256, 0, stream>>>(Qf, Kf, VTf, attnA);
  gemm_k<<<dim3(64, 10), 256, 0, stream>>>(attnA, projT, proj_b, out);
}